// Round 10
// baseline (341.574 us; speedup 1.0000x reference)
//
#include <hip/hip_runtime.h>

#define F0 11
#define F1 64
#define F2 128
#define TN2 128      // nodes per block in k_gemm2

#define CHUNKS 64
#define BPR 12544    // bins (nodes) per range; even; supports N <= 8*BPR = 100352
#define WPR (BPR / 2)// packed u16 words per range (25,088 B LDS)
#define NBS 1024     // bn_stats blocks (multiple of 16)
#define NCR (CHUNKS * 8)   // bucket count (chunk x range slots)

// bf16 helpers (round-to-nearest-even)
__device__ __forceinline__ unsigned short f2bf(float v) {
  unsigned u = __float_as_uint(v);
  unsigned r = u + 0x7FFFu + ((u >> 16) & 1u);
  return (unsigned short)(r >> 16);
}
__device__ __forceinline__ float bf2f(unsigned short s) {
  return __uint_as_float(((unsigned)s) << 16);
}
__device__ __forceinline__ float bf2f_lo(unsigned v) {
  return __uint_as_float(v << 16);
}
__device__ __forceinline__ float bf2f_hi(unsigned v) {
  return __uint_as_float(v & 0xFFFF0000u);
}

// ---------------- pad x (11 fp32) -> x16b (16 bf16, one 32B half-line per row) -------------
__global__ void k_pad(const float* __restrict__ x, unsigned short* __restrict__ x16b, int n) {
  int i = blockIdx.x * blockDim.x + threadIdx.x;
  if (i >= n * 16) return;
  int r = i >> 4, f = i & 15;
  x16b[i] = (f < F0) ? f2bf(x[(size_t)r * F0 + f]) : (unsigned short)0;
}

// ---------------- per-chunk, per-range edge counts (register counters) ----------------
__global__ __launch_bounds__(1024) void k_cnt8(const int* __restrict__ col,
                                               int* __restrict__ bcnt, int E, int CE) {
  __shared__ int scnt[16][8];
  int c = blockIdx.x, t = threadIdx.x;
  int wv = t >> 6, lane = t & 63;
  int e0 = c * CE, e1 = min(E, e0 + CE);
  int cr[8] = {0, 0, 0, 0, 0, 0, 0, 0};
  for (int e = e0 + t; e < e1; e += 1024) {
    int b = col[e];
    int r = b / BPR;
#pragma unroll
    for (int rr = 0; rr < 8; rr++) cr[rr] += (r == rr) ? 1 : 0;
  }
#pragma unroll
  for (int rr = 0; rr < 8; rr++) {
    int v = cr[rr];
#pragma unroll
    for (int d = 32; d > 0; d >>= 1) v += __shfl_down(v, d);
    if (lane == 0) scnt[wv][rr] = v;
  }
  __syncthreads();
  if (t < 8) {
    int s = 0;
    for (int i = 0; i < 16; i++) s += scnt[i][t];
    bcnt[c * 8 + t] = s;
  }
}

// ---------------- exclusive scan of 512 bucket counts -> boff, bcur ----------------
__global__ void k_scan8(const int* __restrict__ bcnt, int* __restrict__ boff,
                        int* __restrict__ bcur, int nb) {   // nb = NCR = 512
  __shared__ int s[NCR];
  int t = threadIdx.x;
  int v = (t < nb) ? bcnt[t] : 0;
  s[t] = v;
  __syncthreads();
  for (int d = 1; d < NCR; d <<= 1) {
    int x = (t >= d) ? s[t - d] : 0;
    __syncthreads();
    s[t] += x;
    __syncthreads();
  }
  int ex = s[t] - v;
  if (t < nb) { boff[t] = ex; bcur[t] = ex; }
  if (t == nb - 1) boff[nb] = ex + v;
}

// ---------------- scatter edges into (chunk,range) buckets; ballot-aggregated cursors ------
__global__ __launch_bounds__(1024) void k_scatter(const int* __restrict__ col,
                                                  const int* __restrict__ row,
                                                  const float* __restrict__ w,
                                                  int* __restrict__ bcur,
                                                  unsigned short* __restrict__ bloc,
                                                  uint2* __restrict__ brw, int E, int CE) {
  int bid = blockIdx.x;
  int c = bid >> 2, q = bid & 3;
  int e0 = c * CE, e1 = min(E, e0 + CE);
  int S = (CE + 3) >> 2;
  int s0 = e0 + q * S, s1 = min(e1, s0 + S);
  int t = threadIdx.x;
  int lane = t & 63;
  for (int base = s0; base < s1; base += 1024) {
    int e = base + t;
    bool act = e < s1;
    int b = 0, rv = 0;
    float wv = 0.f;
    if (act) { b = col[e]; rv = row[e]; wv = w[e]; }
    int r = b / BPR;
#pragma unroll
    for (int rr = 0; rr < 8; rr++) {
      bool mine = act && (r == rr);
      unsigned long long mask = __ballot(mine);
      if (mask == 0ull) continue;
      if (mine) {
        int leader = __ffsll((unsigned long long)mask) - 1;
        int myrank = __popcll(mask & ((1ull << lane) - 1ull));
        int basep = 0;
        if (lane == leader) basep = atomicAdd(&bcur[c * 8 + rr], (int)__popcll(mask));
        basep = __shfl(basep, leader);
        int pos = basep + myrank;
        bloc[pos] = (unsigned short)(b - rr * BPR);
        brw[pos] = make_uint2((unsigned)rv, __float_as_uint(wv));
      }
    }
  }
}

// ---------------- histogram from bucket locals: partial[range][chunk][WPR] ----------------
__global__ __launch_bounds__(1024) void k_hist2(const unsigned short* __restrict__ bloc,
                                                const int* __restrict__ boff,
                                                unsigned* __restrict__ partial, int ranges) {
  __shared__ unsigned lds[WPR];
  int r = blockIdx.x % ranges;          // range -> XCD (round-robin affinity)
  int c = blockIdx.x / ranges;
  int cr = c * 8 + r;
  int t = threadIdx.x;
  for (int i = t; i < WPR; i += 1024) lds[i] = 0;
  __syncthreads();
  int s0 = boff[cr], s1 = boff[cr + 1];
  for (int i = s0 + t; i < s1; i += 1024) {
    int local = bloc[i];
    atomicAdd(&lds[local >> 1], 1u << (16 * (local & 1)));
  }
  __syncthreads();
  unsigned* dst = partial + ((size_t)r * CHUNKS + c) * WPR;
  for (int i = t; i < WPR; i += 1024) dst[i] = lds[i];
}

// ---------------- per-bin prefix over chunks: rel[c][bin] (u16), cnt[bin] ----------------
__global__ void k_colprefix(const unsigned* __restrict__ partial,
                            unsigned short* __restrict__ rel,
                            int* __restrict__ cnt, int N, int npad) {
  int bin = blockIdx.x * blockDim.x + threadIdx.x;
  if (bin >= N) return;
  int r = bin / BPR, local = bin % BPR;
  int word = local >> 1, sh = 16 * (local & 1);
  const unsigned* p = partial + (size_t)r * CHUNKS * WPR + word;
  unsigned acc = 0;
  for (int c = 0; c < CHUNKS; c++) {
    unsigned v = (p[(size_t)c * WPR] >> sh) & 0xFFFFu;
    rel[(size_t)c * npad + bin] = (unsigned short)acc;
    acc += v;
  }
  cnt[bin] = (int)acc;
}

// ---------------- exclusive scan of cnt -> offs ----------------
__global__ void k_scan1(const int* __restrict__ cnt, int* __restrict__ offs,
                        int* __restrict__ bsum, int n) {
  __shared__ int s[1024];
  int tid = threadIdx.x;
  int i = blockIdx.x * 1024 + tid;
  int v = (i < n) ? cnt[i] : 0;
  s[tid] = v;
  __syncthreads();
  for (int d = 1; d < 1024; d <<= 1) {
    int t = (tid >= d) ? s[tid - d] : 0;
    __syncthreads();
    s[tid] += t;
    __syncthreads();
  }
  if (i < n) offs[i] = s[tid] - v;
  if (tid == 1023) bsum[blockIdx.x] = s[1023];
}

__global__ void k_scan2(int* __restrict__ bsum, int nb) {
  __shared__ int s[256];
  __shared__ int carry;
  int t = threadIdx.x;
  if (t == 0) carry = 0;
  __syncthreads();
  for (int base = 0; base < nb; base += 256) {
    int v = (base + t < nb) ? bsum[base + t] : 0;
    s[t] = v;
    __syncthreads();
    for (int d = 1; d < 256; d <<= 1) {
      int x = (t >= d) ? s[t - d] : 0;
      __syncthreads();
      s[t] += x;
      __syncthreads();
    }
    int total = s[255];
    if (base + t < nb) bsum[base + t] = carry + s[t] - v;
    __syncthreads();
    if (t == 0) carry += total;
    __syncthreads();
  }
}

__global__ void k_scan3(int* __restrict__ offs, const int* __restrict__ bsum,
                        int n, int total) {
  int i = blockIdx.x * 1024 + threadIdx.x;
  if (i < n) offs[i] += bsum[blockIdx.x];
  if (i == 0) offs[n] = total;
}

// ---------------- CSR fill from buckets: LDS u16 cursors, all lanes active ----------------
__global__ __launch_bounds__(1024) void k_fill2(const unsigned short* __restrict__ bloc,
                                                const uint2* __restrict__ brw,
                                                const int* __restrict__ boff,
                                                const int* __restrict__ offs,
                                                const unsigned short* __restrict__ rel,
                                                uint2* __restrict__ csr8,
                                                int N, int npad, int ranges) {
  __shared__ unsigned cur[WPR];
  int r = blockIdx.x % ranges;
  int c = blockIdx.x / ranges;
  int cr = c * 8 + r;
  int lo = r * BPR;
  int hi = min(N, lo + BPR);
  int t = threadIdx.x;
  const unsigned* rsrc = (const unsigned*)(rel + (size_t)c * npad + lo);
  int nw = (hi - lo + 1) >> 1;
  for (int i = t; i < nw; i += 1024) cur[i] = rsrc[i];
  __syncthreads();
  int s0 = boff[cr], s1 = boff[cr + 1];
  for (int i = s0 + t; i < s1; i += 1024) {
    int local = bloc[i];
    int sh = 16 * (local & 1);
    unsigned old = atomicAdd(&cur[local >> 1], 1u << sh);
    unsigned myrel = (old >> sh) & 0xFFFFu;
    int pos = offs[lo + local] + (int)myrel;
    csr8[pos] = brw[i];
  }
}

// ---------------- weighted degree -> dinv, wave per node (reads raw w) ----------------
__global__ void k_deg2(const uint2* __restrict__ csr8, const int* __restrict__ offs,
                       float* __restrict__ dinv, int n) {
  int wid = (blockIdx.x * blockDim.x + threadIdx.x) >> 6;
  int lane = threadIdx.x & 63;
  if (wid >= n) return;
  int s = offs[wid], e = offs[wid + 1];
  float acc = 0.f;
  for (int k = s + lane; k < e; k += 64) acc += __uint_as_float(csr8[k].y);
#pragma unroll
  for (int d = 32; d > 0; d >>= 1) acc += __shfl_down(acc, d);
  if (lane == 0) dinv[wid] = rsqrtf(1.0f + acc);   // +1 = self loop weight
}

// ---------------- in-place norm: csr8.y <- dinv[src] * w ----------------
__global__ void k_norm(uint2* __restrict__ csr8, const float* __restrict__ dinv, int E) {
  int i = blockIdx.x * blockDim.x + threadIdx.x;
  if (i >= E) return;
  uint2 v = csr8[i];
  csr8[i].y = __float_as_uint(dinv[v.x] * __uint_as_float(v.y));
}

// -------- fused layer-1: aggregate x16b + GEMM(W1)+b1 -> h (bf16), TWO nodes per wave ------
__global__ void k_agg1g(const unsigned short* __restrict__ x16b, const int* __restrict__ offs,
                        const uint2* __restrict__ csr8, const float* __restrict__ dinv,
                        const float* __restrict__ W1, const float* __restrict__ b1,
                        unsigned short* __restrict__ h, int n) {
  __shared__ float Ws[F0 * F1];
  __shared__ float bs[F1];
  __shared__ unsigned s_soff[4][64];   // per wave: [half*32 + j]
  __shared__ float    s_nrm[4][64];
  int t = threadIdx.x;
  for (int i = t; i < F0 * F1; i += 256) Ws[i] = W1[i];
  if (t < F1) bs[t] = b1[t];
  __syncthreads();
  int wv = t >> 6;
  int lane = t & 63;
  int wid2 = (blockIdx.x * blockDim.x + t) >> 6;   // wave id
  int half = lane >> 5;
  int hl = lane & 31;
  int node = wid2 * 2 + half;
  bool valid = node < n;
  int nd = valid ? node : 0;
  int g2 = hl >> 4, f = lane & 15;
  float di = valid ? dinv[nd] : 0.f;
  int s = valid ? offs[nd] : 0;
  int e = valid ? offs[nd + 1] : 0;
  float a0 = (g2 == 0) ? di * bf2f(x16b[(size_t)nd * 16 + f]) : 0.f;  // self loop
  float a1 = 0.f, a2 = 0.f, a3 = 0.f;
  int len = e - s;
  int b0 = half * 32;
  for (int base = 0; base < len; base += 32) {
    int m = len - base; if (m > 32) m = 32;
    if (hl < m) {
      uint2 v = csr8[s + base + hl];
      s_soff[wv][lane] = v.x * 16u;
      s_nrm[wv][lane] = __uint_as_float(v.y);
    } else {
      s_soff[wv][lane] = 0u;
      s_nrm[wv][lane] = 0.f;
    }
    int mp = (m + 7) & ~7;
    for (int jb = 0; jb < mp; jb += 8) {
      int j0 = b0 + jb + g2;
      unsigned o0 = s_soff[wv][j0 + 0], o1 = s_soff[wv][j0 + 2];
      unsigned o2 = s_soff[wv][j0 + 4], o3 = s_soff[wv][j0 + 6];
      float    m0 = s_nrm[wv][j0 + 0],  m1 = s_nrm[wv][j0 + 2];
      float    m2 = s_nrm[wv][j0 + 4],  m3 = s_nrm[wv][j0 + 6];
      a0 += m0 * bf2f(x16b[(size_t)o0 + f]);
      a1 += m1 * bf2f(x16b[(size_t)o1 + f]);
      a2 += m2 * bf2f(x16b[(size_t)o2 + f]);
      a3 += m3 * bf2f(x16b[(size_t)o3 + f]);
    }
  }
  float acc = (a0 + a1) + (a2 + a3);
  acc += __shfl_xor(acc, 16);     // combine the 2 edge groups within the half
  float av = di * acc;            // feature f of this half's node, at every lane
  float oA = bs[hl], oB = bs[hl + 32];
#pragma unroll
  for (int k = 0; k < F0; k++) {
    float a = __shfl(av, (lane & 32) + k);   // broadcast from own half's lanes
    oA += a * Ws[k * F1 + hl];
    oB += a * Ws[k * F1 + 32 + hl];
  }
  if (valid) {
    h[(size_t)nd * F1 + hl] = f2bf(oA);
    h[(size_t)nd * F1 + 32 + hl] = f2bf(oB);
  }
}

// ---------------- BatchNorm statistics (vectorized 4 bf16/load) ----------------
__global__ void k_bn_stats(const unsigned short* __restrict__ h, float2* __restrict__ pbn,
                           int total4) {   // total4 = N*F1/4
  int t = threadIdx.x;
  int idx = blockIdx.x * blockDim.x + t;
  int stride = gridDim.x * blockDim.x;   // multiple of 16 -> fixed 4-feature window
  const unsigned long long* hp = (const unsigned long long*)h;
  float s0 = 0, s1 = 0, s2 = 0, s3 = 0, q0 = 0, q1 = 0, q2 = 0, q3 = 0;
  for (int i = idx; i < total4; i += stride) {
    unsigned long long vv = hp[i];
    unsigned vx = (unsigned)vv, vy = (unsigned)(vv >> 32);
    float a = bf2f_lo(vx), b = bf2f_hi(vx);
    float c = bf2f_lo(vy), d = bf2f_hi(vy);
    s0 += a; q0 += a * a;
    s1 += b; q1 += b * b;
    s2 += c; q2 += c * c;
    s3 += d; q3 += d * d;
  }
  __shared__ float ss[256][4], qq[256][4];
  ss[t][0] = s0; ss[t][1] = s1; ss[t][2] = s2; ss[t][3] = s3;
  qq[t][0] = q0; qq[t][1] = q1; qq[t][2] = q2; qq[t][3] = q3;
  __syncthreads();
  if (t < 64) {
    int o = t >> 2, sub = t & 3;
    float S = 0.f, Q = 0.f;
#pragma unroll
    for (int i = 0; i < 16; i++) {
      S += ss[o + 16 * i][sub];
      Q += qq[o + 16 * i][sub];
    }
    pbn[(size_t)blockIdx.x * 64 + t] = make_float2(S, Q);
  }
}

// mid-level reduction: 64 blocks, block b reduces partial rows [b*16, b*16+16)
__global__ void k_bn_mid(const float2* __restrict__ pbn, float2* __restrict__ pbn2) {
  __shared__ float sS[4][64], sQ[4][64];
  int t = threadIdx.x;
  int f = t & 63, g = t >> 6;
  int b0 = blockIdx.x * 16;
  float S = 0.f, Q = 0.f;
  for (int b = b0 + g; b < b0 + 16; b += 4) {
    float2 v = pbn[(size_t)b * 64 + f];
    S += v.x; Q += v.y;
  }
  sS[g][f] = S; sQ[g][f] = Q;
  __syncthreads();
  if (t < 64)
    pbn2[(size_t)blockIdx.x * 64 + t] =
        make_float2(sS[0][t] + sS[1][t] + sS[2][t] + sS[3][t],
                    sQ[0][t] + sQ[1][t] + sQ[2][t] + sQ[3][t]);
}

__global__ void k_bn_final(const float2* __restrict__ pbn2, const float* __restrict__ gamma,
                           const float* __restrict__ beta, float* __restrict__ scalef,
                           float* __restrict__ shiftf, int n) {
  __shared__ double sS[4][64], sQ[4][64];
  int t = threadIdx.x;
  int f = t & 63, g = t >> 6;
  double S = 0.0, Q = 0.0;
  for (int b = g; b < 64; b += 4) {
    float2 v = pbn2[(size_t)b * 64 + f];
    S += v.x; Q += v.y;
  }
  sS[g][f] = S; sQ[g][f] = Q;
  __syncthreads();
  if (t < 64) {
    double SS = sS[0][t] + sS[1][t] + sS[2][t] + sS[3][t];
    double QQ = sQ[0][t] + sQ[1][t] + sQ[2][t] + sQ[3][t];
    double mean = SS / (double)n;
    double var = QQ / (double)n - mean * mean;
    if (var < 0.0) var = 0.0;
    float scale = gamma[t] * (float)(1.0 / sqrt(var + 1e-5));
    scalef[t] = scale;
    shiftf[t] = beta[t] - (float)mean * scale;
  }
}

// -------- layer-2 aggregation (bf16 h gather) with fused BN+ReLU, 8 chains ----------
__global__ void k_agg2(const unsigned short* __restrict__ h, const int* __restrict__ offs,
                       const uint2* __restrict__ csr8, const float* __restrict__ dinv,
                       const float* __restrict__ scalef, const float* __restrict__ shiftf,
                       float* __restrict__ agg2, int n) {
  __shared__ unsigned s_soff[4][64];
  __shared__ float    s_nrm[4][64];
  int t = threadIdx.x;
  int wv = t >> 6;
  int lane = t & 63;
  int wid = (blockIdx.x * blockDim.x + t) >> 6;
  if (wid >= n) return;
  float sc = scalef[lane], sf = shiftf[lane];
  float di = dinv[wid];
  float a0 = di * fmaxf(fmaf(bf2f(h[(size_t)wid * F1 + lane]), sc, sf), 0.f);  // self loop
  float a1 = 0.f, a2 = 0.f, a3 = 0.f, a4 = 0.f, a5 = 0.f, a6 = 0.f, a7 = 0.f;
  int s = offs[wid], e = offs[wid + 1];
  for (int base = s; base < e; base += 64) {
    int m = e - base; if (m > 64) m = 64;
    if (lane < m) {
      uint2 v = csr8[base + lane];
      s_soff[wv][lane] = v.x * 64u;
      s_nrm[wv][lane] = __uint_as_float(v.y);
    } else {
      s_soff[wv][lane] = 0u;
      s_nrm[wv][lane] = 0.f;
    }
    int mp = (m + 7) & ~7;
    for (int j = 0; j < mp; j += 8) {
      unsigned o0 = s_soff[wv][j + 0], o1 = s_soff[wv][j + 1];
      unsigned o2 = s_soff[wv][j + 2], o3 = s_soff[wv][j + 3];
      unsigned o4 = s_soff[wv][j + 4], o5 = s_soff[wv][j + 5];
      unsigned o6 = s_soff[wv][j + 6], o7 = s_soff[wv][j + 7];
      float m0 = s_nrm[wv][j + 0], m1 = s_nrm[wv][j + 1];
      float m2 = s_nrm[wv][j + 2], m3 = s_nrm[wv][j + 3];
      float m4 = s_nrm[wv][j + 4], m5 = s_nrm[wv][j + 5];
      float m6 = s_nrm[wv][j + 6], m7 = s_nrm[wv][j + 7];
      a0 += m0 * fmaxf(fmaf(bf2f(h[(size_t)o0 + lane]), sc, sf), 0.f);
      a1 += m1 * fmaxf(fmaf(bf2f(h[(size_t)o1 + lane]), sc, sf), 0.f);
      a2 += m2 * fmaxf(fmaf(bf2f(h[(size_t)o2 + lane]), sc, sf), 0.f);
      a3 += m3 * fmaxf(fmaf(bf2f(h[(size_t)o3 + lane]), sc, sf), 0.f);
      a4 += m4 * fmaxf(fmaf(bf2f(h[(size_t)o4 + lane]), sc, sf), 0.f);
      a5 += m5 * fmaxf(fmaf(bf2f(h[(size_t)o5 + lane]), sc, sf), 0.f);
      a6 += m6 * fmaxf(fmaf(bf2f(h[(size_t)o6 + lane]), sc, sf), 0.f);
      a7 += m7 * fmaxf(fmaf(bf2f(h[(size_t)o7 + lane]), sc, sf), 0.f);
    }
  }
  agg2[(size_t)wid * F1 + lane] =
      di * (((a0 + a1) + (a2 + a3)) + ((a4 + a5) + (a6 + a7)));
}

// ---------------- out = agg2 @ W2 + b2, register-tiled GEMM ----------------
__global__ __launch_bounds__(256) void k_gemm2(const float* __restrict__ agg2,
                                               const float* __restrict__ W2,
                                               const float* __restrict__ b2,
                                               float* __restrict__ out, int n) {
  __shared__ float Ws[F1 * F2];
  __shared__ float As[F1][TN2];
  int t = threadIdx.x;
  for (int i = t; i < F1 * F2 / 4; i += 256) ((float4*)Ws)[i] = ((const float4*)W2)[i];
  int nb = blockIdx.x * TN2;
  int node = t & 127;
  int kh = (t >> 7) * 32;
  int gnode = nb + node;
  if (gnode < n) {
    const float4* src = (const float4*)(agg2 + (size_t)gnode * F1 + kh);
#pragma unroll
    for (int j = 0; j < 8; j++) {
      float4 v = src[j];
      As[kh + j * 4 + 0][node] = v.x;
      As[kh + j * 4 + 1][node] = v.y;
      As[kh + j * 4 + 2][node] = v.z;
      As[kh + j * 4 + 3][node] = v.w;
    }
  } else {
#pragma unroll
    for (int j = 0; j < 8; j++) {
      As[kh + j * 4 + 0][node] = 0.f;
      As[kh + j * 4 + 1][node] = 0.f;
      As[kh + j * 4 + 2][node] = 0.f;
      As[kh + j * 4 + 3][node] = 0.f;
    }
  }
  __syncthreads();

  int f0 = (t & 15) * 8;
  int n0 = (t >> 4) * 8;
  float acc[8][8];
  float bv[8];
#pragma unroll
  for (int j = 0; j < 8; j++) bv[j] = b2[f0 + j];
#pragma unroll
  for (int i = 0; i < 8; i++)
#pragma unroll
    for (int j = 0; j < 8; j++) acc[i][j] = bv[j];

#pragma unroll 4
  for (int k = 0; k < F1; k++) {
    float4 a0 = *(const float4*)&As[k][n0];
    float4 a1 = *(const float4*)&As[k][n0 + 4];
    float4 w0 = *(const float4*)&Ws[k * F2 + f0];
    float4 w1 = *(const float4*)&Ws[k * F2 + f0 + 4];
    float a[8] = {a0.x, a0.y, a0.z, a0.w, a1.x, a1.y, a1.z, a1.w};
    float w[8] = {w0.x, w0.y, w0.z, w0.w, w1.x, w1.y, w1.z, w1.w};
#pragma unroll
    for (int i = 0; i < 8; i++)
#pragma unroll
      for (int j = 0; j < 8; j++) acc[i][j] += a[i] * w[j];
  }

#pragma unroll
  for (int i = 0; i < 8; i++) {
    int gi = nb + n0 + i;
    if (gi < n) {
      float4 o0 = {acc[i][0], acc[i][1], acc[i][2], acc[i][3]};
      float4 o1 = {acc[i][4], acc[i][5], acc[i][6], acc[i][7]};
      *(float4*)&out[(size_t)gi * F2 + f0] = o0;
      *(float4*)&out[(size_t)gi * F2 + f0 + 4] = o1;
    }
  }
}

extern "C" void kernel_launch(void* const* d_in, const int* in_sizes, int n_in,
                              void* d_out, int out_size, void* d_ws, size_t ws_size,
                              hipStream_t stream) {
  const float* x     = (const float*)d_in[0];
  const int*   ei    = (const int*)d_in[1];
  const float* ew    = (const float*)d_in[2];
  const float* W1    = (const float*)d_in[3];
  const float* b1    = (const float*)d_in[4];
  const float* gamma = (const float*)d_in[5];
  const float* beta  = (const float*)d_in[6];
  const float* W2    = (const float*)d_in[7];
  const float* b2    = (const float*)d_in[8];
  float* out = (float*)d_out;

  int N = in_sizes[0] / F0;
  int E = in_sizes[1] / 2;
  const int* row = ei;
  const int* col = ei + E;
  if (N <= 0) return;

  int CE = (E + CHUNKS - 1) / CHUNKS;
  int RANGES = (N + BPR - 1) / BPR;     // 8 for N=100K -> maps 1:1 onto XCDs
  int npad = RANGES * BPR;

  // ---- workspace carve-up (with overlays) ----
  char* p = (char*)d_ws;
  auto alloc = [&](size_t bytes) -> void* {
    void* r = (void*)p;
    p += (bytes + 255) & ~(size_t)255;
    return r;
  };
  size_t partial_bytes = ((size_t)RANGES * CHUNKS * WPR * 4 + 255) & ~(size_t)255;
  size_t rel_bytes     = (size_t)CHUNKS * npad * 2;
  size_t h_bytes       = (size_t)N * F1 * 2;          // bf16 h
  size_t region_bytes  = partial_bytes + rel_bytes;
  if (h_bytes > region_bytes) region_bytes = h_bytes;

  float*          dinv    = (float*)alloc((size_t)N * 4);
  int*            cnt     = (int*)alloc((size_t)N * 4);
  int*            offs    = (int*)alloc((size_t)(N + 1) * 4);
  int             NB      = (N + 1023) / 1024;
  int*            bsum    = (int*)alloc((size_t)NB * 4);
  uint2*          csr8    = (uint2*)alloc((size_t)E * 8);
  char*           region  = (char*)alloc(region_bytes);
  unsigned*       partial = (unsigned*)region;                          // dead after k_colprefix
  unsigned short* rel     = (unsigned short*)(region + partial_bytes);  // dead after k_fill2
  unsigned short* h       = (unsigned short*)region;                    // written after fill
  unsigned short* x16b    = (unsigned short*)alloc((size_t)N * 16 * 2);
  float*          agg2    = (float*)alloc((size_t)N * F1 * 4);          // also hosts buckets
  float2*         pbn     = (float2*)alloc((size_t)NBS * 64 * 8);
  float2*         pbn2    = (float2*)alloc((size_t)64 * 64 * 8);
  float*          scalef  = (float*)alloc(64 * 4);
  float*          shiftf  = (float*)alloc(64 * 4);
  int*            bcnt    = (int*)alloc((size_t)NCR * 4);
  int*            boff    = (int*)alloc((size_t)(NCR + 1) * 4);
  int*            bcur    = (int*)alloc((size_t)NCR * 4);
  // buckets overlay agg2 (dead until k_agg2, which runs after k_fill2)
  size_t bloc_bytes = (((size_t)E * 2) + 255) & ~(size_t)255;
  unsigned short* bloc = (unsigned short*)agg2;
  uint2*          brw  = (uint2*)((char*)agg2 + bloc_bytes);
  (void)ws_size; (void)n_in; (void)out_size;

  int bW  = (N + 3) / 4;                 // 1 node / wave kernels
  int bW1 = ((N + 1) / 2 + 3) / 4;       // 2 nodes / wave (k_agg1g)
  int bG2 = (N + TN2 - 1) / TN2;
  int gRC = CHUNKS * RANGES;

  k_pad<<<(N * 16 + 255) / 256, 256, 0, stream>>>(x, x16b, N);
  k_cnt8<<<CHUNKS, 1024, 0, stream>>>(col, bcnt, E, CE);
  k_scan8<<<1, NCR, 0, stream>>>(bcnt, boff, bcur, NCR);
  k_scatter<<<CHUNKS * 4, 1024, 0, stream>>>(col, row, ew, bcur, bloc, brw, E, CE);
  k_hist2<<<gRC, 1024, 0, stream>>>(bloc, boff, partial, RANGES);
  k_colprefix<<<(N + 255) / 256, 256, 0, stream>>>(partial, rel, cnt, N, npad);
  k_scan1<<<NB, 1024, 0, stream>>>(cnt, offs, bsum, N);
  k_scan2<<<1, 256, 0, stream>>>(bsum, NB);
  k_scan3<<<NB, 1024, 0, stream>>>(offs, bsum, N, E);
  k_fill2<<<gRC, 1024, 0, stream>>>(bloc, brw, boff, offs, rel, csr8, N, npad, RANGES);
  k_deg2<<<bW, 256, 0, stream>>>(csr8, offs, dinv, N);
  k_norm<<<(E + 255) / 256, 256, 0, stream>>>(csr8, dinv, E);
  k_agg1g<<<bW1, 256, 0, stream>>>(x16b, offs, csr8, dinv, W1, b1, h, N);
  k_bn_stats<<<NBS, 256, 0, stream>>>(h, pbn, N * F1 / 4);
  k_bn_mid<<<64, 256, 0, stream>>>(pbn, pbn2);
  k_bn_final<<<1, 256, 0, stream>>>(pbn2, gamma, beta, scalef, shiftf, N);
  k_agg2<<<bW, 256, 0, stream>>>(h, offs, csr8, dinv, scalef, shiftf, agg2, N);
  k_gemm2<<<bG2, 256, 0, stream>>>(agg2, W2, b2, out, N);
}

// Round 11
// 235.948 us; speedup vs baseline: 1.4477x; 1.4477x over previous
//
#include <hip/hip_runtime.h>

#define F0 11
#define F1 64
#define F2 128
#define TN2 128      // nodes per block in k_gemm2

#define CHUNKS 64
#define BPR 12544    // bins (nodes) per range; even; supports N <= 8*BPR = 100352
#define WPR (BPR / 2)// packed u16 words per range (25,088 B LDS)
#define NBS 1024     // bn_stats blocks (multiple of 16)
#define NBKT (CHUNKS * 8 * 4)   // 2048 buckets: ((c*8+r)*4+q)

// bf16 helpers (round-to-nearest-even)
__device__ __forceinline__ unsigned short f2bf(float v) {
  unsigned u = __float_as_uint(v);
  unsigned r = u + 0x7FFFu + ((u >> 16) & 1u);
  return (unsigned short)(r >> 16);
}
__device__ __forceinline__ float bf2f(unsigned short s) {
  return __uint_as_float(((unsigned)s) << 16);
}
__device__ __forceinline__ float bf2f_lo(unsigned v) {
  return __uint_as_float(v << 16);
}
__device__ __forceinline__ float bf2f_hi(unsigned v) {
  return __uint_as_float(v & 0xFFFF0000u);
}

// ---------------- pad x (11 fp32) -> x16b (16 bf16, one 32B half-line per row) -------------
__global__ void k_pad(const float* __restrict__ x, unsigned short* __restrict__ x16b, int n) {
  int i = blockIdx.x * blockDim.x + threadIdx.x;
  if (i >= n * 16) return;
  int r = i >> 4, f = i & 15;
  x16b[i] = (f < F0) ? f2bf(x[(size_t)r * F0 + f]) : (unsigned short)0;
}

// ---------------- per-(quarter-chunk), per-range edge counts ----------------
__global__ __launch_bounds__(1024) void k_cnt8(const int* __restrict__ col,
                                               int* __restrict__ bcnt, int E, int CE) {
  __shared__ int scnt[16][8];
  int bid = blockIdx.x;
  int c = bid >> 2, q = bid & 3;
  int e0 = c * CE, e1 = min(E, e0 + CE);
  int S = (CE + 3) >> 2;
  int s0 = e0 + q * S, s1 = min(e1, s0 + S);
  int t = threadIdx.x, wv = t >> 6, lane = t & 63;
  int cr[8] = {0, 0, 0, 0, 0, 0, 0, 0};
  for (int e = s0 + t; e < s1; e += 1024) {
    int r = col[e] / BPR;
#pragma unroll
    for (int rr = 0; rr < 8; rr++) cr[rr] += (r == rr) ? 1 : 0;
  }
#pragma unroll
  for (int rr = 0; rr < 8; rr++) {
    int v = cr[rr];
#pragma unroll
    for (int d = 32; d > 0; d >>= 1) v += __shfl_down(v, d);
    if (lane == 0) scnt[wv][rr] = v;
  }
  __syncthreads();
  if (t < 8) {
    int s = 0;
    for (int i = 0; i < 16; i++) s += scnt[i][t];
    bcnt[(c * 8 + t) * 4 + q] = s;
  }
}

// ---------------- exclusive scan of 2048 bucket counts -> boff ----------------
__global__ void k_scan8(const int* __restrict__ bcnt, int* __restrict__ boff) {
  __shared__ int s[1024];
  int t = threadIdx.x;
  int v0 = bcnt[2 * t], v1 = bcnt[2 * t + 1];
  int pv = v0 + v1;
  s[t] = pv;
  __syncthreads();
  for (int d = 1; d < 1024; d <<= 1) {
    int x = (t >= d) ? s[t - d] : 0;
    __syncthreads();
    s[t] += x;
    __syncthreads();
  }
  int ex = s[t] - pv;
  boff[2 * t] = ex;
  boff[2 * t + 1] = ex + v0;
  if (t == 1023) boff[2048] = s[1023];
}

// ---------------- scatter edges into private buckets; LDS cursors, no global atomics ------
__global__ __launch_bounds__(1024) void k_scatter(const int* __restrict__ col,
                                                  const int* __restrict__ row,
                                                  const float* __restrict__ w,
                                                  const int* __restrict__ boff,
                                                  unsigned short* __restrict__ bloc,
                                                  uint2* __restrict__ brw, int E, int CE) {
  __shared__ int cur[8];
  int bid = blockIdx.x;
  int c = bid >> 2, q = bid & 3;
  int t = threadIdx.x;
  if (t < 8) cur[t] = boff[(c * 8 + t) * 4 + q];
  __syncthreads();
  int e0 = c * CE, e1 = min(E, e0 + CE);
  int S = (CE + 3) >> 2;
  int s0 = e0 + q * S, s1 = min(e1, s0 + S);
  for (int e = s0 + t; e < s1; e += 1024) {
    int b = col[e];
    int r = b / BPR;
    int pos = atomicAdd(&cur[r], 1);
    bloc[pos] = (unsigned short)(b - r * BPR);
    brw[pos] = make_uint2((unsigned)row[e], __float_as_uint(w[e]));
  }
}

// ---------------- histogram from bucket locals: partial[range][chunk][WPR] ----------------
__global__ __launch_bounds__(1024) void k_hist2(const unsigned short* __restrict__ bloc,
                                                const int* __restrict__ boff,
                                                unsigned* __restrict__ partial, int ranges) {
  __shared__ unsigned lds[WPR];
  int r = blockIdx.x % ranges;          // range -> XCD (round-robin affinity)
  int c = blockIdx.x / ranges;
  int t = threadIdx.x;
  for (int i = t; i < WPR; i += 1024) lds[i] = 0;
  __syncthreads();
  int s0 = boff[(c * 8 + r) * 4], s1 = boff[(c * 8 + r) * 4 + 4];
  for (int i = s0 + t; i < s1; i += 1024) {
    int local = bloc[i];
    atomicAdd(&lds[local >> 1], 1u << (16 * (local & 1)));
  }
  __syncthreads();
  unsigned* dst = partial + ((size_t)r * CHUNKS + c) * WPR;
  for (int i = t; i < WPR; i += 1024) dst[i] = lds[i];
}

// ---------------- per-bin prefix over chunks: rel[c][bin] (u16), cnt[bin] ----------------
__global__ void k_colprefix(const unsigned* __restrict__ partial,
                            unsigned short* __restrict__ rel,
                            int* __restrict__ cnt, int N, int npad) {
  int bin = blockIdx.x * blockDim.x + threadIdx.x;
  if (bin >= N) return;
  int r = bin / BPR, local = bin % BPR;
  int word = local >> 1, sh = 16 * (local & 1);
  const unsigned* p = partial + (size_t)r * CHUNKS * WPR + word;
  unsigned acc = 0;
  for (int c = 0; c < CHUNKS; c++) {
    unsigned v = (p[(size_t)c * WPR] >> sh) & 0xFFFFu;
    rel[(size_t)c * npad + bin] = (unsigned short)acc;
    acc += v;
  }
  cnt[bin] = (int)acc;
}

// ---------------- exclusive scan of cnt -> offs ----------------
__global__ void k_scan1(const int* __restrict__ cnt, int* __restrict__ offs,
                        int* __restrict__ bsum, int n) {
  __shared__ int s[1024];
  int tid = threadIdx.x;
  int i = blockIdx.x * 1024 + tid;
  int v = (i < n) ? cnt[i] : 0;
  s[tid] = v;
  __syncthreads();
  for (int d = 1; d < 1024; d <<= 1) {
    int t = (tid >= d) ? s[tid - d] : 0;
    __syncthreads();
    s[tid] += t;
    __syncthreads();
  }
  if (i < n) offs[i] = s[tid] - v;
  if (tid == 1023) bsum[blockIdx.x] = s[1023];
}

__global__ void k_scan2(int* __restrict__ bsum, int nb) {
  __shared__ int s[256];
  __shared__ int carry;
  int t = threadIdx.x;
  if (t == 0) carry = 0;
  __syncthreads();
  for (int base = 0; base < nb; base += 256) {
    int v = (base + t < nb) ? bsum[base + t] : 0;
    s[t] = v;
    __syncthreads();
    for (int d = 1; d < 256; d <<= 1) {
      int x = (t >= d) ? s[t - d] : 0;
      __syncthreads();
      s[t] += x;
      __syncthreads();
    }
    int total = s[255];
    if (base + t < nb) bsum[base + t] = carry + s[t] - v;
    __syncthreads();
    if (t == 0) carry += total;
    __syncthreads();
  }
}

__global__ void k_scan3(int* __restrict__ offs, const int* __restrict__ bsum,
                        int n, int total) {
  int i = blockIdx.x * 1024 + threadIdx.x;
  if (i < n) offs[i] += bsum[blockIdx.x];
  if (i == 0) offs[n] = total;
}

// ---------------- CSR fill from buckets: LDS u16 cursors, all lanes active ----------------
__global__ __launch_bounds__(1024) void k_fill2(const unsigned short* __restrict__ bloc,
                                                const uint2* __restrict__ brw,
                                                const int* __restrict__ boff,
                                                const int* __restrict__ offs,
                                                const unsigned short* __restrict__ rel,
                                                uint2* __restrict__ csr8,
                                                int N, int npad, int ranges) {
  __shared__ unsigned cur[WPR];
  int r = blockIdx.x % ranges;
  int c = blockIdx.x / ranges;
  int lo = r * BPR;
  int hi = min(N, lo + BPR);
  int t = threadIdx.x;
  const unsigned* rsrc = (const unsigned*)(rel + (size_t)c * npad + lo);
  int nw = (hi - lo + 1) >> 1;
  for (int i = t; i < nw; i += 1024) cur[i] = rsrc[i];
  __syncthreads();
  int s0 = boff[(c * 8 + r) * 4], s1 = boff[(c * 8 + r) * 4 + 4];
  for (int i = s0 + t; i < s1; i += 1024) {
    int local = bloc[i];
    int sh = 16 * (local & 1);
    unsigned old = atomicAdd(&cur[local >> 1], 1u << sh);
    unsigned myrel = (old >> sh) & 0xFFFFu;
    int pos = offs[lo + local] + (int)myrel;
    csr8[pos] = brw[i];
  }
}

// ---------------- weighted degree -> dinv, wave per node (reads raw w) ----------------
__global__ void k_deg2(const uint2* __restrict__ csr8, const int* __restrict__ offs,
                       float* __restrict__ dinv, int n) {
  int wid = (blockIdx.x * blockDim.x + threadIdx.x) >> 6;
  int lane = threadIdx.x & 63;
  if (wid >= n) return;
  int s = offs[wid], e = offs[wid + 1];
  float acc = 0.f;
  for (int k = s + lane; k < e; k += 64) acc += __uint_as_float(csr8[k].y);
#pragma unroll
  for (int d = 32; d > 0; d >>= 1) acc += __shfl_down(acc, d);
  if (lane == 0) dinv[wid] = rsqrtf(1.0f + acc);   // +1 = self loop weight
}

// ---------------- in-place norm: csr8.y <- dinv[src] * w ----------------
__global__ void k_norm(uint2* __restrict__ csr8, const float* __restrict__ dinv, int E) {
  int i = blockIdx.x * blockDim.x + threadIdx.x;
  if (i >= E) return;
  uint2 v = csr8[i];
  csr8[i].y = __float_as_uint(dinv[v.x] * __uint_as_float(v.y));
}

// -------- fused layer-1: aggregate x16b (bf16) + GEMM(W1)+b1 -> h (bf16), wave per node ----
// Lane layout: g = lane>>4 (edge group 0..3), f = lane&15. 4 chains -> 16 edges in flight.
__global__ void k_agg1g(const unsigned short* __restrict__ x16b, const int* __restrict__ offs,
                        const uint2* __restrict__ csr8, const float* __restrict__ dinv,
                        const float* __restrict__ W1, const float* __restrict__ b1,
                        unsigned short* __restrict__ h, int n) {
  __shared__ float Ws[F0 * F1];
  __shared__ float bs[F1];
  __shared__ unsigned s_soff[4][64];   // src*16 (element offset into x16b); 0 in pad
  __shared__ float    s_nrm[4][64];    // dinv[src]*w; 0 in pad
  int t = threadIdx.x;
  for (int i = t; i < F0 * F1; i += 256) Ws[i] = W1[i];
  if (t < F1) bs[t] = b1[t];
  __syncthreads();
  int wv = t >> 6;
  int lane = t & 63;
  int wid = (blockIdx.x * blockDim.x + t) >> 6;
  if (wid >= n) return;
  int g = lane >> 4, f = lane & 15;
  float di = dinv[wid];
  float a0 = (g == 0) ? di * bf2f(x16b[(size_t)wid * 16 + f]) : 0.f;  // self loop
  float a1 = 0.f, a2 = 0.f, a3 = 0.f;
  int s = offs[wid], e = offs[wid + 1];
  for (int base = s; base < e; base += 64) {
    int m = e - base; if (m > 64) m = 64;
    if (lane < m) {
      uint2 v = csr8[base + lane];
      s_soff[wv][lane] = v.x * 16u;
      s_nrm[wv][lane] = __uint_as_float(v.y);
    } else {
      s_soff[wv][lane] = 0u;
      s_nrm[wv][lane] = 0.f;
    }
    int mp = (m + 15) & ~15;
    for (int jb = 0; jb < mp; jb += 16) {
      unsigned o0 = s_soff[wv][jb + g],      o1 = s_soff[wv][jb + 4 + g];
      unsigned o2 = s_soff[wv][jb + 8 + g],  o3 = s_soff[wv][jb + 12 + g];
      float    m0 = s_nrm[wv][jb + g],       m1 = s_nrm[wv][jb + 4 + g];
      float    m2 = s_nrm[wv][jb + 8 + g],   m3 = s_nrm[wv][jb + 12 + g];
      a0 += m0 * bf2f(x16b[(size_t)o0 + f]);
      a1 += m1 * bf2f(x16b[(size_t)o1 + f]);
      a2 += m2 * bf2f(x16b[(size_t)o2 + f]);
      a3 += m3 * bf2f(x16b[(size_t)o3 + f]);
    }
  }
  float acc = (a0 + a1) + (a2 + a3);
  acc += __shfl_xor(acc, 16);     // reduce across the 4 edge groups
  acc += __shfl_xor(acc, 32);
  float av = di * acc;            // feature f total at every lane with lane&15==f
  float o = bs[lane];
#pragma unroll
  for (int k = 0; k < F0; k++) o += __shfl(av, k) * Ws[k * F1 + lane];
  h[(size_t)wid * F1 + lane] = f2bf(o);
}

// ---------------- BatchNorm statistics (vectorized 4 bf16/load) ----------------
__global__ void k_bn_stats(const unsigned short* __restrict__ h, float2* __restrict__ pbn,
                           int total4) {   // total4 = N*F1/4
  int t = threadIdx.x;
  int idx = blockIdx.x * blockDim.x + t;
  int stride = gridDim.x * blockDim.x;   // multiple of 16 -> fixed 4-feature window
  const unsigned long long* hp = (const unsigned long long*)h;
  float s0 = 0, s1 = 0, s2 = 0, s3 = 0, q0 = 0, q1 = 0, q2 = 0, q3 = 0;
  for (int i = idx; i < total4; i += stride) {
    unsigned long long vv = hp[i];
    unsigned vx = (unsigned)vv, vy = (unsigned)(vv >> 32);
    float a = bf2f_lo(vx), b = bf2f_hi(vx);
    float c = bf2f_lo(vy), d = bf2f_hi(vy);
    s0 += a; q0 += a * a;
    s1 += b; q1 += b * b;
    s2 += c; q2 += c * c;
    s3 += d; q3 += d * d;
  }
  __shared__ float ss[256][4], qq[256][4];
  ss[t][0] = s0; ss[t][1] = s1; ss[t][2] = s2; ss[t][3] = s3;
  qq[t][0] = q0; qq[t][1] = q1; qq[t][2] = q2; qq[t][3] = q3;
  __syncthreads();
  if (t < 64) {
    int o = t >> 2, sub = t & 3;
    float S = 0.f, Q = 0.f;
#pragma unroll
    for (int i = 0; i < 16; i++) {
      S += ss[o + 16 * i][sub];
      Q += qq[o + 16 * i][sub];
    }
    pbn[(size_t)blockIdx.x * 64 + t] = make_float2(S, Q);
  }
}

// mid-level reduction: 64 blocks, block b reduces partial rows [b*16, b*16+16)
__global__ void k_bn_mid(const float2* __restrict__ pbn, float2* __restrict__ pbn2) {
  __shared__ float sS[4][64], sQ[4][64];
  int t = threadIdx.x;
  int f = t & 63, g = t >> 6;
  int b0 = blockIdx.x * 16;
  float S = 0.f, Q = 0.f;
  for (int b = b0 + g; b < b0 + 16; b += 4) {
    float2 v = pbn[(size_t)b * 64 + f];
    S += v.x; Q += v.y;
  }
  sS[g][f] = S; sQ[g][f] = Q;
  __syncthreads();
  if (t < 64)
    pbn2[(size_t)blockIdx.x * 64 + t] =
        make_float2(sS[0][t] + sS[1][t] + sS[2][t] + sS[3][t],
                    sQ[0][t] + sQ[1][t] + sQ[2][t] + sQ[3][t]);
}

__global__ void k_bn_final(const float2* __restrict__ pbn2, const float* __restrict__ gamma,
                           const float* __restrict__ beta, float* __restrict__ scalef,
                           float* __restrict__ shiftf, int n) {
  __shared__ double sS[4][64], sQ[4][64];
  int t = threadIdx.x;
  int f = t & 63, g = t >> 6;
  double S = 0.0, Q = 0.0;
  for (int b = g; b < 64; b += 4) {
    float2 v = pbn2[(size_t)b * 64 + f];
    S += v.x; Q += v.y;
  }
  sS[g][f] = S; sQ[g][f] = Q;
  __syncthreads();
  if (t < 64) {
    double SS = sS[0][t] + sS[1][t] + sS[2][t] + sS[3][t];
    double QQ = sQ[0][t] + sQ[1][t] + sQ[2][t] + sQ[3][t];
    double mean = SS / (double)n;
    double var = QQ / (double)n - mean * mean;
    if (var < 0.0) var = 0.0;
    float scale = gamma[t] * (float)(1.0 / sqrt(var + 1e-5));
    scalef[t] = scale;
    shiftf[t] = beta[t] - (float)mean * scale;
  }
}

// -------- layer-2 aggregation (bf16 h gather) with fused BN+ReLU, 8 chains ----------
__global__ void k_agg2(const unsigned short* __restrict__ h, const int* __restrict__ offs,
                       const uint2* __restrict__ csr8, const float* __restrict__ dinv,
                       const float* __restrict__ scalef, const float* __restrict__ shiftf,
                       float* __restrict__ agg2, int n) {
  __shared__ unsigned s_soff[4][64];
  __shared__ float    s_nrm[4][64];
  int t = threadIdx.x;
  int wv = t >> 6;
  int lane = t & 63;
  int wid = (blockIdx.x * blockDim.x + t) >> 6;
  if (wid >= n) return;
  float sc = scalef[lane], sf = shiftf[lane];
  float di = dinv[wid];
  float a0 = di * fmaxf(fmaf(bf2f(h[(size_t)wid * F1 + lane]), sc, sf), 0.f);  // self loop
  float a1 = 0.f, a2 = 0.f, a3 = 0.f, a4 = 0.f, a5 = 0.f, a6 = 0.f, a7 = 0.f;
  int s = offs[wid], e = offs[wid + 1];
  for (int base = s; base < e; base += 64) {
    int m = e - base; if (m > 64) m = 64;
    if (lane < m) {
      uint2 v = csr8[base + lane];
      s_soff[wv][lane] = v.x * 64u;
      s_nrm[wv][lane] = __uint_as_float(v.y);
    } else {
      s_soff[wv][lane] = 0u;
      s_nrm[wv][lane] = 0.f;
    }
    int mp = (m + 7) & ~7;
    for (int j = 0; j < mp; j += 8) {
      unsigned o0 = s_soff[wv][j + 0], o1 = s_soff[wv][j + 1];
      unsigned o2 = s_soff[wv][j + 2], o3 = s_soff[wv][j + 3];
      unsigned o4 = s_soff[wv][j + 4], o5 = s_soff[wv][j + 5];
      unsigned o6 = s_soff[wv][j + 6], o7 = s_soff[wv][j + 7];
      float m0 = s_nrm[wv][j + 0], m1 = s_nrm[wv][j + 1];
      float m2 = s_nrm[wv][j + 2], m3 = s_nrm[wv][j + 3];
      float m4 = s_nrm[wv][j + 4], m5 = s_nrm[wv][j + 5];
      float m6 = s_nrm[wv][j + 6], m7 = s_nrm[wv][j + 7];
      a0 += m0 * fmaxf(fmaf(bf2f(h[(size_t)o0 + lane]), sc, sf), 0.f);
      a1 += m1 * fmaxf(fmaf(bf2f(h[(size_t)o1 + lane]), sc, sf), 0.f);
      a2 += m2 * fmaxf(fmaf(bf2f(h[(size_t)o2 + lane]), sc, sf), 0.f);
      a3 += m3 * fmaxf(fmaf(bf2f(h[(size_t)o3 + lane]), sc, sf), 0.f);
      a4 += m4 * fmaxf(fmaf(bf2f(h[(size_t)o4 + lane]), sc, sf), 0.f);
      a5 += m5 * fmaxf(fmaf(bf2f(h[(size_t)o5 + lane]), sc, sf), 0.f);
      a6 += m6 * fmaxf(fmaf(bf2f(h[(size_t)o6 + lane]), sc, sf), 0.f);
      a7 += m7 * fmaxf(fmaf(bf2f(h[(size_t)o7 + lane]), sc, sf), 0.f);
    }
  }
  agg2[(size_t)wid * F1 + lane] =
      di * (((a0 + a1) + (a2 + a3)) + ((a4 + a5) + (a6 + a7)));
}

// ---------------- out = agg2 @ W2 + b2, register-tiled GEMM ----------------
__global__ __launch_bounds__(256) void k_gemm2(const float* __restrict__ agg2,
                                               const float* __restrict__ W2,
                                               const float* __restrict__ b2,
                                               float* __restrict__ out, int n) {
  __shared__ float Ws[F1 * F2];
  __shared__ float As[F1][TN2];
  int t = threadIdx.x;
  for (int i = t; i < F1 * F2 / 4; i += 256) ((float4*)Ws)[i] = ((const float4*)W2)[i];
  int nb = blockIdx.x * TN2;
  int node = t & 127;
  int kh = (t >> 7) * 32;
  int gnode = nb + node;
  if (gnode < n) {
    const float4* src = (const float4*)(agg2 + (size_t)gnode * F1 + kh);
#pragma unroll
    for (int j = 0; j < 8; j++) {
      float4 v = src[j];
      As[kh + j * 4 + 0][node] = v.x;
      As[kh + j * 4 + 1][node] = v.y;
      As[kh + j * 4 + 2][node] = v.z;
      As[kh + j * 4 + 3][node] = v.w;
    }
  } else {
#pragma unroll
    for (int j = 0; j < 8; j++) {
      As[kh + j * 4 + 0][node] = 0.f;
      As[kh + j * 4 + 1][node] = 0.f;
      As[kh + j * 4 + 2][node] = 0.f;
      As[kh + j * 4 + 3][node] = 0.f;
    }
  }
  __syncthreads();

  int f0 = (t & 15) * 8;
  int n0 = (t >> 4) * 8;
  float acc[8][8];
  float bv[8];
#pragma unroll
  for (int j = 0; j < 8; j++) bv[j] = b2[f0 + j];
#pragma unroll
  for (int i = 0; i < 8; i++)
#pragma unroll
    for (int j = 0; j < 8; j++) acc[i][j] = bv[j];

#pragma unroll 4
  for (int k = 0; k < F1; k++) {
    float4 a0 = *(const float4*)&As[k][n0];
    float4 a1 = *(const float4*)&As[k][n0 + 4];
    float4 w0 = *(const float4*)&Ws[k * F2 + f0];
    float4 w1 = *(const float4*)&Ws[k * F2 + f0 + 4];
    float a[8] = {a0.x, a0.y, a0.z, a0.w, a1.x, a1.y, a1.z, a1.w};
    float w[8] = {w0.x, w0.y, w0.z, w0.w, w1.x, w1.y, w1.z, w1.w};
#pragma unroll
    for (int i = 0; i < 8; i++)
#pragma unroll
      for (int j = 0; j < 8; j++) acc[i][j] += a[i] * w[j];
  }

#pragma unroll
  for (int i = 0; i < 8; i++) {
    int gi = nb + n0 + i;
    if (gi < n) {
      float4 o0 = {acc[i][0], acc[i][1], acc[i][2], acc[i][3]};
      float4 o1 = {acc[i][4], acc[i][5], acc[i][6], acc[i][7]};
      *(float4*)&out[(size_t)gi * F2 + f0] = o0;
      *(float4*)&out[(size_t)gi * F2 + f0 + 4] = o1;
    }
  }
}

extern "C" void kernel_launch(void* const* d_in, const int* in_sizes, int n_in,
                              void* d_out, int out_size, void* d_ws, size_t ws_size,
                              hipStream_t stream) {
  const float* x     = (const float*)d_in[0];
  const int*   ei    = (const int*)d_in[1];
  const float* ew    = (const float*)d_in[2];
  const float* W1    = (const float*)d_in[3];
  const float* b1    = (const float*)d_in[4];
  const float* gamma = (const float*)d_in[5];
  const float* beta  = (const float*)d_in[6];
  const float* W2    = (const float*)d_in[7];
  const float* b2    = (const float*)d_in[8];
  float* out = (float*)d_out;

  int N = in_sizes[0] / F0;
  int E = in_sizes[1] / 2;
  const int* row = ei;
  const int* col = ei + E;
  if (N <= 0) return;

  int CE = (E + CHUNKS - 1) / CHUNKS;
  int RANGES = (N + BPR - 1) / BPR;     // 8 for N=100K -> maps 1:1 onto XCDs
  int npad = RANGES * BPR;

  // ---- workspace carve-up (with overlays) ----
  char* p = (char*)d_ws;
  auto alloc = [&](size_t bytes) -> void* {
    void* r = (void*)p;
    p += (bytes + 255) & ~(size_t)255;
    return r;
  };
  size_t partial_bytes = ((size_t)RANGES * CHUNKS * WPR * 4 + 255) & ~(size_t)255;
  size_t rel_bytes     = (size_t)CHUNKS * npad * 2;
  size_t h_bytes       = (size_t)N * F1 * 2;          // bf16 h
  size_t region_bytes  = partial_bytes + rel_bytes;
  if (h_bytes > region_bytes) region_bytes = h_bytes;

  float*          dinv    = (float*)alloc((size_t)N * 4);
  int*            cnt     = (int*)alloc((size_t)N * 4);
  int*            offs    = (int*)alloc((size_t)(N + 1) * 4);
  int             NB      = (N + 1023) / 1024;
  int*            bsum    = (int*)alloc((size_t)NB * 4);
  uint2*          csr8    = (uint2*)alloc((size_t)E * 8);
  char*           region  = (char*)alloc(region_bytes);
  unsigned*       partial = (unsigned*)region;                          // dead after k_colprefix
  unsigned short* rel     = (unsigned short*)(region + partial_bytes);  // dead after k_fill2
  unsigned short* h       = (unsigned short*)region;                    // written after fill
  unsigned short* x16b    = (unsigned short*)alloc((size_t)N * 16 * 2);
  float*          agg2    = (float*)alloc((size_t)N * F1 * 4);          // also hosts buckets
  float2*         pbn     = (float2*)alloc((size_t)NBS * 64 * 8);
  float2*         pbn2    = (float2*)alloc((size_t)64 * 64 * 8);
  float*          scalef  = (float*)alloc(64 * 4);
  float*          shiftf  = (float*)alloc(64 * 4);
  int*            bcnt    = (int*)alloc((size_t)NBKT * 4);
  int*            boff    = (int*)alloc((size_t)(NBKT + 1) * 4);
  // buckets overlay agg2 (dead until k_agg2, which runs after k_fill2)
  size_t bloc_bytes = (((size_t)E * 2) + 255) & ~(size_t)255;
  unsigned short* bloc = (unsigned short*)agg2;
  uint2*          brw  = (uint2*)((char*)agg2 + bloc_bytes);
  (void)ws_size; (void)n_in; (void)out_size;

  int bW  = (N + 3) / 4;                 // wave-per-node kernels
  int bG2 = (N + TN2 - 1) / TN2;
  int gRC = CHUNKS * RANGES;

  k_pad<<<(N * 16 + 255) / 256, 256, 0, stream>>>(x, x16b, N);
  k_cnt8<<<CHUNKS * 4, 1024, 0, stream>>>(col, bcnt, E, CE);
  k_scan8<<<1, 1024, 0, stream>>>(bcnt, boff);
  k_scatter<<<CHUNKS * 4, 1024, 0, stream>>>(col, row, ew, boff, bloc, brw, E, CE);
  k_hist2<<<gRC, 1024, 0, stream>>>(bloc, boff, partial, RANGES);
  k_colprefix<<<(N + 255) / 256, 256, 0, stream>>>(partial, rel, cnt, N, npad);
  k_scan1<<<NB, 1024, 0, stream>>>(cnt, offs, bsum, N);
  k_scan2<<<1, 256, 0, stream>>>(bsum, NB);
  k_scan3<<<NB, 1024, 0, stream>>>(offs, bsum, N, E);
  k_fill2<<<gRC, 1024, 0, stream>>>(bloc, brw, boff, offs, rel, csr8, N, npad, RANGES);
  k_deg2<<<bW, 256, 0, stream>>>(csr8, offs, dinv, N);
  k_norm<<<(E + 255) / 256, 256, 0, stream>>>(csr8, dinv, E);
  k_agg1g<<<bW, 256, 0, stream>>>(x16b, offs, csr8, dinv, W1, b1, h, N);
  k_bn_stats<<<NBS, 256, 0, stream>>>(h, pbn, N * F1 / 4);
  k_bn_mid<<<64, 256, 0, stream>>>(pbn, pbn2);
  k_bn_final<<<1, 256, 0, stream>>>(pbn2, gamma, beta, scalef, shiftf, N);
  k_agg2<<<bW, 256, 0, stream>>>(h, offs, csr8, dinv, scalef, shiftf, agg2, N);
  k_gemm2<<<bG2, 256, 0, stream>>>(agg2, W2, b2, out, N);
}